// Round 6
// baseline (146.573 us; speedup 1.0000x reference)
//
#include <hip/hip_runtime.h>

// 2-layer GCN, N=100000 (F0=5, F1=16, F2=1), E=3200000.
// dst-sorted-bin formulation; aggregation is atomic-free; the per-bin sort is
// now an atomic-free 2x4-bit LSD radix sort using 64-lane ballot ranking.
//   bin b owns nodes [b*256, b*256+256) at bins[b*CAP ...]; entry = (dst&255)<<24 | src.
//   y[i]   = dinv[i]*x[i] (5 floats padded to 8)
//   z[i]   = dinv[i]*(relu(dinv[i]*(sum_run y[s] + y[i])@W1 + b1)@W2)
//   out[i] = dinv[i]*(sum_run z[s] + z[i]) + b2

constexpr int CHUNK = 4096;   // edges per k_place block
constexpr int RANGE = 256;    // nodes per bin
constexpr int CAP   = 12288;  // slots per bin region (max bin ~8.6K)
constexpr int NITER = CAP / 1024;  // 12 virtual-wave groups max

__global__ void k_init(int* __restrict__ cursor, int nb) {
  int b = blockIdx.x * blockDim.x + threadIdx.x;
  if (b < nb) cursor[b] = b * CAP;
}

// ---- pass 1: LDS counting-sort each chunk into bin regions (coalesced) -----
__global__ void __launch_bounds__(256) k_place(const int* __restrict__ src,
                                               const int* __restrict__ dst,
                                               int* __restrict__ cursor,
                                               int* __restrict__ bins,
                                               int e, int nb) {
  __shared__ int entry4[CHUNK];
  __shared__ short bin2[CHUNK];
  __shared__ int hist[512], scan[512], lofs[512], base[512], pcur[512];
  int t = threadIdx.x;
  int e0 = blockIdx.x * CHUNK;
  int cnt = e - e0; if (cnt > CHUNK) cnt = CHUNK;

  for (int b = t; b < 512; b += 256) hist[b] = 0;
  __syncthreads();
  for (int i = t; i < cnt; i += 256) atomicAdd(&hist[dst[e0 + i] >> 8], 1);
  __syncthreads();
  scan[t] = hist[t]; scan[t + 256] = hist[t + 256];
  __syncthreads();
  for (int d = 1; d < 512; d <<= 1) {
    int v0 = (t >= d) ? scan[t - d] : 0;
    int v1 = (t + 256 >= d) ? scan[t + 256 - d] : 0;
    __syncthreads();
    scan[t] += v0; scan[t + 256] += v1;
    __syncthreads();
  }
  for (int b = t; b < 512; b += 256) {
    int lo = scan[b] - hist[b];
    lofs[b] = lo;
    pcur[b] = lo;
    if (b < nb && hist[b]) base[b] = atomicAdd(&cursor[b], hist[b]);  // absolute
  }
  __syncthreads();
  for (int i = t; i < cnt; i += 256) {
    int d = dst[e0 + i];
    int b = d >> 8;
    int slot = atomicAdd(&pcur[b], 1);
    entry4[slot] = ((d & 255) << 24) | src[e0 + i];
    bin2[slot] = (short)b;
  }
  __syncthreads();
  for (int i = t; i < cnt; i += 256) {
    int b = bin2[i];
    bins[base[b] + (i - lofs[b])] = entry4[i];
  }
}

// ---- pass 2: per-bin ballot radix sort (2x4-bit LSD), roff via bsearch -----
__global__ void __launch_bounds__(1024) k_sortbin(int* __restrict__ bins,
                                                  const int* __restrict__ cursor,
                                                  const float* __restrict__ x,
                                                  float* __restrict__ dinv,
                                                  float* __restrict__ y,
                                                  int* __restrict__ roff, int n) {
  __shared__ int A[CAP];                 // 48 KB
  __shared__ int B[CAP];                 // 48 KB
  __shared__ int vcnt[NITER * 16][16];   // 12 KB  [vwave][digit]
  __shared__ int dbase[17];
  __shared__ int roffs[RANGE + 1];

  int t = threadIdx.x;
  int lane = t & 63, w = t >> 6;         // 16 waves
  int b = blockIdx.x;
  int bse = b * CAP;
  int len = cursor[b] - bse;
  int nIter = (len + 1023) >> 10;

  // ================= PASS 1: digit = dl low 4 bits, global bins -> A ========
  for (int j = t; j < NITER * 16 * 16; j += 1024) ((int*)vcnt)[j] = 0;
  __syncthreads();
  for (int i = 0; i < nIter; ++i) {
    int k = i * 1024 + t;
    bool act = k < len;
    unsigned e4 = act ? (unsigned)bins[bse + k] : 0u;
    int d = (e4 >> 24) & 15;
    unsigned long long m = __ballot(act);
#pragma unroll
    for (int bit = 0; bit < 4; ++bit) {
      unsigned long long bb = __ballot(act && ((d >> bit) & 1));
      m &= ((d >> bit) & 1) ? bb : ~bb;
    }
    if (act) {
      unsigned long long lower = m & ((1ull << lane) - 1ull);
      if (lower == 0) vcnt[i * 16 + w][d] = __popcll(m);
    }
  }
  __syncthreads();
  if (t < 16) {  // column scan: vcnt[.][t] -> exclusive, total in dbase[t]
    int run = 0;
    for (int j = 0; j < nIter * 16; ++j) { int c = vcnt[j][t]; vcnt[j][t] = run; run += c; }
    dbase[t] = run;
  }
  __syncthreads();
  if (t == 0) {
    int run = 0;
    for (int d = 0; d < 16; ++d) { int c = dbase[d]; dbase[d] = run; run += c; }
    dbase[16] = run;
  }
  __syncthreads();
  for (int i = 0; i < nIter; ++i) {  // scatter
    int k = i * 1024 + t;
    bool act = k < len;
    unsigned e4 = act ? (unsigned)bins[bse + k] : 0u;
    int d = (e4 >> 24) & 15;
    unsigned long long m = __ballot(act);
#pragma unroll
    for (int bit = 0; bit < 4; ++bit) {
      unsigned long long bb = __ballot(act && ((d >> bit) & 1));
      m &= ((d >> bit) & 1) ? bb : ~bb;
    }
    if (act) {
      int rank = __popcll(m & ((1ull << lane) - 1ull));
      A[dbase[d] + vcnt[i * 16 + w][d] + rank] = (int)e4;
    }
  }
  __syncthreads();

  // ================= PASS 2: digit = dl high 4 bits, A -> B (stable) ========
  for (int j = t; j < NITER * 16 * 16; j += 1024) ((int*)vcnt)[j] = 0;
  __syncthreads();
  for (int i = 0; i < nIter; ++i) {
    int k = i * 1024 + t;
    bool act = k < len;
    unsigned e4 = act ? (unsigned)A[k] : 0u;
    int d = (e4 >> 28) & 15;
    unsigned long long m = __ballot(act);
#pragma unroll
    for (int bit = 0; bit < 4; ++bit) {
      unsigned long long bb = __ballot(act && ((d >> bit) & 1));
      m &= ((d >> bit) & 1) ? bb : ~bb;
    }
    if (act) {
      unsigned long long lower = m & ((1ull << lane) - 1ull);
      if (lower == 0) vcnt[i * 16 + w][d] = __popcll(m);
    }
  }
  __syncthreads();
  if (t < 16) {
    int run = 0;
    for (int j = 0; j < nIter * 16; ++j) { int c = vcnt[j][t]; vcnt[j][t] = run; run += c; }
    dbase[t] = run;
  }
  __syncthreads();
  if (t == 0) {
    int run = 0;
    for (int d = 0; d < 16; ++d) { int c = dbase[d]; dbase[d] = run; run += c; }
    dbase[16] = run;
  }
  __syncthreads();
  for (int i = 0; i < nIter; ++i) {
    int k = i * 1024 + t;
    bool act = k < len;
    unsigned e4 = act ? (unsigned)A[k] : 0u;
    int d = (e4 >> 28) & 15;
    unsigned long long m = __ballot(act);
#pragma unroll
    for (int bit = 0; bit < 4; ++bit) {
      unsigned long long bb = __ballot(act && ((d >> bit) & 1));
      m &= ((d >> bit) & 1) ? bb : ~bb;
    }
    if (act) {
      int rank = __popcll(m & ((1ull << lane) - 1ull));
      B[dbase[d] + vcnt[i * 16 + w][d] + rank] = (int)e4;
    }
  }
  __syncthreads();

  // ---- run offsets via binary search over sorted dl, write-out, dinv, y ----
  if (t < RANGE) {
    int lo = 0, hi = len;
    while (lo < hi) {
      int mid = (lo + hi) >> 1;
      int dl = ((unsigned)B[mid]) >> 24;
      if (dl < t) lo = mid + 1; else hi = mid;
    }
    roffs[t] = lo;
  }
  if (t == 0) roffs[RANGE] = len;
  __syncthreads();
  for (int k = t; k < len; k += 1024) bins[bse + k] = B[k] & 0xFFFFFF;
  if (t < RANGE) {
    roff[b * (RANGE + 1) + t] = bse + roffs[t];
    if (t == 0) roff[b * (RANGE + 1) + RANGE] = bse + len;
    int node = b * RANGE + t;
    if (node < n) {
      int deg = roffs[t + 1] - roffs[t];
      float dv = rsqrtf((float)(deg + 1));
      dinv[node] = dv;
      float4 a, c;
      a.x = dv * x[node * 5 + 0];
      a.y = dv * x[node * 5 + 1];
      a.z = dv * x[node * 5 + 2];
      a.w = dv * x[node * 5 + 3];
      c.x = dv * x[node * 5 + 4];
      c.y = c.z = c.w = 0.f;
      ((float4*)y)[(size_t)node * 2 + 0] = a;
      ((float4*)y)[(size_t)node * 2 + 1] = c;
    }
  }
}

// ---- pass 3: layer-1 — atomic-free segmented gather + fused W1/relu/W2 -----
__global__ void __launch_bounds__(1024) k_agg1(const int* __restrict__ bins,
                                               const int* __restrict__ roff,
                                               const float* __restrict__ y,
                                               const float* __restrict__ dinv,
                                               const float* __restrict__ W1,
                                               const float* __restrict__ b1,
                                               const float* __restrict__ W2,
                                               float* __restrict__ z, int n) {
  __shared__ float sW1[80], sb1[16], sW2[16];
  int t = threadIdx.x;
  if (t < 80) sW1[t] = W1[t];
  else if (t < 96) sb1[t - 80] = b1[t - 80];
  else if (t < 112) sW2[t - 96] = W2[t - 96];
  __syncthreads();
  int g = t >> 2, l4 = t & 3;
  int b = blockIdx.x;
  int node = b * RANGE + g;
  if (node >= n) return;
  int r0 = roff[b * (RANGE + 1) + g];
  int r1 = roff[b * (RANGE + 1) + g + 1];
  float a0 = 0.f, a1 = 0.f, a2 = 0.f, a3 = 0.f, a4 = 0.f;
  for (int k = r0 + l4; k < r1; k += 4) {
    int s = bins[k];
    float4 v = ((const float4*)y)[(size_t)s * 2];
    float v4 = y[(size_t)s * 8 + 4];
    a0 += v.x; a1 += v.y; a2 += v.z; a3 += v.w; a4 += v4;
  }
  a0 += __shfl_xor(a0, 1); a0 += __shfl_xor(a0, 2);
  a1 += __shfl_xor(a1, 1); a1 += __shfl_xor(a1, 2);
  a2 += __shfl_xor(a2, 1); a2 += __shfl_xor(a2, 2);
  a3 += __shfl_xor(a3, 1); a3 += __shfl_xor(a3, 2);
  a4 += __shfl_xor(a4, 1); a4 += __shfl_xor(a4, 2);
  float4 ys = ((const float4*)y)[(size_t)node * 2];
  float ys4 = y[(size_t)node * 8 + 4];
  float A0 = a0 + ys.x, A1 = a1 + ys.y, A2 = a2 + ys.z, A3 = a3 + ys.w, A4 = a4 + ys4;
  float di = dinv[node];
  float o = 0.f;
#pragma unroll
  for (int fi = 0; fi < 4; ++fi) {
    int f = l4 * 4 + fi;
    float h = A0 * sW1[0 * 16 + f];
    h = fmaf(A1, sW1[1 * 16 + f], h);
    h = fmaf(A2, sW1[2 * 16 + f], h);
    h = fmaf(A3, sW1[3 * 16 + f], h);
    h = fmaf(A4, sW1[4 * 16 + f], h);
    float v = fmaxf(fmaf(di, h, sb1[f]), 0.f);
    o = fmaf(v, sW2[f], o);
  }
  o += __shfl_xor(o, 1);
  o += __shfl_xor(o, 2);
  if (l4 == 0) z[node] = di * o;
}

// ---- pass 4: layer-2 — atomic-free segmented gather of scalar z ------------
__global__ void __launch_bounds__(1024) k_agg2(const int* __restrict__ bins,
                                               const int* __restrict__ roff,
                                               const float* __restrict__ z,
                                               const float* __restrict__ dinv,
                                               const float* __restrict__ b2,
                                               float* __restrict__ out, int n) {
  int t = threadIdx.x;
  int g = t >> 2, l4 = t & 3;
  int b = blockIdx.x;
  int node = b * RANGE + g;
  if (node >= n) return;
  int r0 = roff[b * (RANGE + 1) + g];
  int r1 = roff[b * (RANGE + 1) + g + 1];
  float a = 0.f;
  for (int k = r0 + l4; k < r1; k += 4) a += z[bins[k]];
  a += __shfl_xor(a, 1);
  a += __shfl_xor(a, 2);
  if (l4 == 0) out[node] = fmaf(dinv[node], a + z[node], b2[0]);
}

extern "C" void kernel_launch(void* const* d_in, const int* in_sizes, int n_in,
                              void* d_out, int out_size, void* d_ws, size_t ws_size,
                              hipStream_t stream) {
  const float* x  = (const float*)d_in[0];
  const float* W1 = (const float*)d_in[1];
  const float* b1 = (const float*)d_in[2];
  const float* W2 = (const float*)d_in[3];
  const float* b2 = (const float*)d_in[4];
  const int*   ei = (const int*)d_in[5];

  int n = in_sizes[0] / 5;
  int e = in_sizes[5] / 2;
  const int* src = ei;
  const int* dst = ei + e;
  int nb = (n + RANGE - 1) / RANGE;  // 391

  char* ws = (char*)d_ws;
  int*   bins   = (int*)ws;   ws += (size_t)nb * CAP * sizeof(int);
  float* y      = (float*)ws; ws += (size_t)nb * RANGE * 8 * sizeof(float);
  float* dinv   = (float*)ws; ws += (size_t)n * sizeof(float);
  float* z      = (float*)ws; ws += (size_t)n * sizeof(float);
  int*   cursor = (int*)ws;   ws += (size_t)nb * sizeof(int);
  int*   roff   = (int*)ws;   ws += (size_t)nb * (RANGE + 1) * sizeof(int);

  float* out = (float*)d_out;

  int chunks = (e + CHUNK - 1) / CHUNK;

  k_init<<<(nb + 255) / 256, 256, 0, stream>>>(cursor, nb);
  k_place<<<chunks, 256, 0, stream>>>(src, dst, cursor, bins, e, nb);
  k_sortbin<<<nb, 1024, 0, stream>>>(bins, cursor, x, dinv, y, roff, n);
  k_agg1<<<nb, 1024, 0, stream>>>(bins, roff, y, dinv, W1, b1, W2, z, n);
  k_agg2<<<nb, 1024, 0, stream>>>(bins, roff, z, dinv, b2, out, n);
}

// Round 7
// 138.583 us; speedup vs baseline: 1.0577x; 1.0577x over previous
//
#include <hip/hip_runtime.h>

// 2-layer GCN, N=100000 (F0=5, F1=16, F2=1), E=3200000.
// dst-sorted-bin formulation; aggregation is atomic-free; per-bin sort is an
// atomic-free 2x4-bit LSD ballot radix sort, in-place in one LDS buffer.
//   bin b owns nodes [b*256, b*256+256) at bins[b*CAP ...]; entry = (dst&255)<<24 | src.
//   y[i]   = dinv[i]*x[i] (5 floats padded to 8)
//   z[i]   = dinv[i]*(relu(dinv[i]*(sum_run y[s] + y[i])@W1 + b1)@W2)
//   out[i] = dinv[i]*(sum_run z[s] + z[i]) + b2

constexpr int CHUNK = 4096;        // edges per k_place block
constexpr int RANGE = 256;         // nodes per bin
constexpr int CAP   = 12288;       // slots per bin region (max bin ~8.6K, +45 sigma)
constexpr int NITER = CAP / 1024;  // 12

__global__ void k_init(int* __restrict__ cursor, int nb) {
  int b = blockIdx.x * blockDim.x + threadIdx.x;
  if (b < nb) cursor[b] = b * CAP;
}

// ---- pass 1: LDS counting-sort each chunk into bin regions (coalesced) -----
__global__ void __launch_bounds__(256) k_place(const int* __restrict__ src,
                                               const int* __restrict__ dst,
                                               int* __restrict__ cursor,
                                               int* __restrict__ bins,
                                               int e, int nb) {
  __shared__ int entry4[CHUNK];
  __shared__ short bin2[CHUNK];
  __shared__ int hist[512], scan[512], lofs[512], base[512], pcur[512];
  int t = threadIdx.x;
  int e0 = blockIdx.x * CHUNK;
  int cnt = e - e0; if (cnt > CHUNK) cnt = CHUNK;

  for (int b = t; b < 512; b += 256) hist[b] = 0;
  __syncthreads();
  for (int i = t; i < cnt; i += 256) atomicAdd(&hist[dst[e0 + i] >> 8], 1);
  __syncthreads();
  scan[t] = hist[t]; scan[t + 256] = hist[t + 256];
  __syncthreads();
  for (int d = 1; d < 512; d <<= 1) {
    int v0 = (t >= d) ? scan[t - d] : 0;
    int v1 = (t + 256 >= d) ? scan[t + 256 - d] : 0;
    __syncthreads();
    scan[t] += v0; scan[t + 256] += v1;
    __syncthreads();
  }
  for (int b = t; b < 512; b += 256) {
    int lo = scan[b] - hist[b];
    lofs[b] = lo;
    pcur[b] = lo;
    if (b < nb && hist[b]) base[b] = atomicAdd(&cursor[b], hist[b]);  // absolute
  }
  __syncthreads();
  for (int i = t; i < cnt; i += 256) {
    int d = dst[e0 + i];
    int b = d >> 8;
    int slot = atomicAdd(&pcur[b], 1);
    entry4[slot] = ((d & 255) << 24) | src[e0 + i];
    bin2[slot] = (short)b;
  }
  __syncthreads();
  for (int i = t; i < cnt; i += 256) {
    int b = bin2[i];
    bins[base[b] + (i - lofs[b])] = entry4[i];
  }
}

// 64-lane match mask for a 4-bit digit (lanes with a==false excluded).
__device__ inline unsigned long long match4(bool a, int d) {
  unsigned long long m = __ballot(a);
#pragma unroll
  for (int bit = 0; bit < 4; ++bit) {
    unsigned long long bb = __ballot(a && ((d >> bit) & 1));
    m &= ((d >> bit) & 1) ? bb : ~bb;
  }
  return m;
}

// ---- pass 2: per-bin in-place ballot radix sort (2x4-bit LSD) --------------
__global__ void __launch_bounds__(1024) k_sortbin(int* __restrict__ bins,
                                                  const int* __restrict__ cursor,
                                                  const float* __restrict__ x,
                                                  float* __restrict__ dinv,
                                                  float* __restrict__ y,
                                                  int* __restrict__ roff, int n) {
  __shared__ int A[CAP];                 // 48 KB (single buffer, in-place pass 2)
  __shared__ int vcnt[NITER * 16][16];   // 12 KB  [vwave][digit]
  __shared__ int ssum[16][16];           // [digit][chunk]
  __shared__ int dtot[16];
  __shared__ int dbase[17];
  __shared__ int roffs[RANGE + 1];

  const int t = threadIdx.x;
  const int lane = t & 63, w = t >> 6;   // 16 waves
  const int b = blockIdx.x;
  const int bse = b * CAP;
  const int len = cursor[b] - bse;
  const int nIter = (len + 1023) >> 10;
  const unsigned long long low = (1ull << lane) - 1ull;

  unsigned ev[NITER];

  // ======================= PASS 1: digit = bits 24..27 ======================
#pragma unroll
  for (int i = 0; i < NITER; ++i) {   // prefetch global -> regs (static idx)
    int k = (i << 10) + t;
    ev[i] = (i < nIter && k < len) ? (unsigned)bins[bse + k] : 0u;
  }
  for (int j = t; j < nIter * 256; j += 1024) ((int*)vcnt)[j] = 0;
  __syncthreads();
#pragma unroll
  for (int i = 0; i < NITER; ++i) if (i < nIter) {   // count
    bool a = ((i << 10) + t) < len;
    int d = (ev[i] >> 24) & 15;
    unsigned long long m = match4(a, d);
    if (a && (m & low) == 0) vcnt[(i << 4) + w][d] = __popcll(m);
  }
  __syncthreads();
  {  // chunked-parallel exclusive scan of vcnt rows per digit + digit bases
    int V = nIter * 16;
    if (t < 256) {
      int d = t & 15, c = t >> 4;
      int r0 = c * NITER, r1 = min(r0 + NITER, V);
      int s = 0;
      for (int r = r0; r < r1; ++r) { int v = vcnt[r][d]; vcnt[r][d] = s; s += v; }
      ssum[d][c] = s;
    }
    __syncthreads();
    if (t < 16) {
      int run = 0;
      for (int c = 0; c < 16; ++c) { int v = ssum[t][c]; ssum[t][c] = run; run += v; }
      dtot[t] = run;
    }
    __syncthreads();
    if (t == 0) {
      int run = 0;
      for (int d = 0; d < 16; ++d) { dbase[d] = run; run += dtot[d]; }
      dbase[16] = run;
    }
    if (t < 256) {
      int d = t & 15, c = t >> 4;
      int add = ssum[d][c];
      int r0 = c * NITER, r1 = min(r0 + NITER, V);
      for (int r = r0; r < r1; ++r) vcnt[r][d] += add;
    }
    __syncthreads();
  }
#pragma unroll
  for (int i = 0; i < NITER; ++i) if (i < nIter) {   // scatter global-regs -> A
    bool a = ((i << 10) + t) < len;
    int d = (ev[i] >> 24) & 15;
    unsigned long long m = match4(a, d);
    if (a) {
      int rank = __popcll(m & low);
      A[dbase[d] + vcnt[(i << 4) + w][d] + rank] = (int)ev[i];
    }
  }
  __syncthreads();

  // ======================= PASS 2: digit = bits 28..31 (stable) =============
#pragma unroll
  for (int i = 0; i < NITER; ++i) {   // prefetch A -> regs (sequential reads)
    int k = (i << 10) + t;
    ev[i] = (i < nIter && k < len) ? (unsigned)A[k] : 0u;
  }
  for (int j = t; j < nIter * 256; j += 1024) ((int*)vcnt)[j] = 0;
  __syncthreads();
#pragma unroll
  for (int i = 0; i < NITER; ++i) if (i < nIter) {   // count
    bool a = ((i << 10) + t) < len;
    int d = ev[i] >> 28;
    unsigned long long m = match4(a, d);
    if (a && (m & low) == 0) vcnt[(i << 4) + w][d] = __popcll(m);
  }
  __syncthreads();
  {
    int V = nIter * 16;
    if (t < 256) {
      int d = t & 15, c = t >> 4;
      int r0 = c * NITER, r1 = min(r0 + NITER, V);
      int s = 0;
      for (int r = r0; r < r1; ++r) { int v = vcnt[r][d]; vcnt[r][d] = s; s += v; }
      ssum[d][c] = s;
    }
    __syncthreads();
    if (t < 16) {
      int run = 0;
      for (int c = 0; c < 16; ++c) { int v = ssum[t][c]; ssum[t][c] = run; run += v; }
      dtot[t] = run;
    }
    __syncthreads();
    if (t == 0) {
      int run = 0;
      for (int d = 0; d < 16; ++d) { dbase[d] = run; run += dtot[d]; }
      dbase[16] = run;
    }
    if (t < 256) {
      int d = t & 15, c = t >> 4;
      int add = ssum[d][c];
      int r0 = c * NITER, r1 = min(r0 + NITER, V);
      for (int r = r0; r < r1; ++r) vcnt[r][d] += add;
    }
    __syncthreads();
  }
#pragma unroll
  for (int i = 0; i < NITER; ++i) if (i < nIter) {   // scatter regs -> A (in place)
    bool a = ((i << 10) + t) < len;
    int d = ev[i] >> 28;
    unsigned long long m = match4(a, d);
    if (a) {
      int rank = __popcll(m & low);
      A[dbase[d] + vcnt[(i << 4) + w][d] + rank] = (int)ev[i];
    }
  }
  __syncthreads();

  // ---- run offsets via binary search over sorted dl; write-out; dinv; y ----
  if (t < RANGE) {
    int lo = 0, hi = len;
    while (lo < hi) {
      int mid = (lo + hi) >> 1;
      int dl = ((unsigned)A[mid]) >> 24;
      if (dl < t) lo = mid + 1; else hi = mid;
    }
    roffs[t] = lo;
  }
  if (t == 0) roffs[RANGE] = len;
  __syncthreads();
  for (int k = t; k < len; k += 1024) bins[bse + k] = A[k];  // keep dl tag; agg masks
  if (t < RANGE) {
    roff[b * (RANGE + 1) + t] = bse + roffs[t];
    if (t == 0) roff[b * (RANGE + 1) + RANGE] = bse + len;
    int node = b * RANGE + t;
    if (node < n) {
      int deg = roffs[t + 1] - roffs[t];
      float dv = rsqrtf((float)(deg + 1));
      dinv[node] = dv;
      float4 a, c;
      a.x = dv * x[node * 5 + 0];
      a.y = dv * x[node * 5 + 1];
      a.z = dv * x[node * 5 + 2];
      a.w = dv * x[node * 5 + 3];
      c.x = dv * x[node * 5 + 4];
      c.y = c.z = c.w = 0.f;
      ((float4*)y)[(size_t)node * 2 + 0] = a;
      ((float4*)y)[(size_t)node * 2 + 1] = c;
    }
  }
}

// ---- pass 3: layer-1 — atomic-free segmented gather + fused W1/relu/W2 -----
__global__ void __launch_bounds__(1024) k_agg1(const int* __restrict__ bins,
                                               const int* __restrict__ roff,
                                               const float* __restrict__ y,
                                               const float* __restrict__ dinv,
                                               const float* __restrict__ W1,
                                               const float* __restrict__ b1,
                                               const float* __restrict__ W2,
                                               float* __restrict__ z, int n) {
  __shared__ float sW1[80], sb1[16], sW2[16];
  int t = threadIdx.x;
  if (t < 80) sW1[t] = W1[t];
  else if (t < 96) sb1[t - 80] = b1[t - 80];
  else if (t < 112) sW2[t - 96] = W2[t - 96];
  __syncthreads();
  int g = t >> 2, l4 = t & 3;
  int b = blockIdx.x;
  int node = b * RANGE + g;
  if (node >= n) return;
  int r0 = roff[b * (RANGE + 1) + g];
  int r1 = roff[b * (RANGE + 1) + g + 1];
  float a0 = 0.f, a1 = 0.f, a2 = 0.f, a3 = 0.f, a4 = 0.f;
  for (int k = r0 + l4; k < r1; k += 4) {
    int s = bins[k] & 0xFFFFFF;
    float4 v = ((const float4*)y)[(size_t)s * 2];
    float v4 = y[(size_t)s * 8 + 4];
    a0 += v.x; a1 += v.y; a2 += v.z; a3 += v.w; a4 += v4;
  }
  a0 += __shfl_xor(a0, 1); a0 += __shfl_xor(a0, 2);
  a1 += __shfl_xor(a1, 1); a1 += __shfl_xor(a1, 2);
  a2 += __shfl_xor(a2, 1); a2 += __shfl_xor(a2, 2);
  a3 += __shfl_xor(a3, 1); a3 += __shfl_xor(a3, 2);
  a4 += __shfl_xor(a4, 1); a4 += __shfl_xor(a4, 2);
  float4 ys = ((const float4*)y)[(size_t)node * 2];
  float ys4 = y[(size_t)node * 8 + 4];
  float A0 = a0 + ys.x, A1 = a1 + ys.y, A2 = a2 + ys.z, A3 = a3 + ys.w, A4 = a4 + ys4;
  float di = dinv[node];
  float o = 0.f;
#pragma unroll
  for (int fi = 0; fi < 4; ++fi) {
    int f = l4 * 4 + fi;
    float h = A0 * sW1[0 * 16 + f];
    h = fmaf(A1, sW1[1 * 16 + f], h);
    h = fmaf(A2, sW1[2 * 16 + f], h);
    h = fmaf(A3, sW1[3 * 16 + f], h);
    h = fmaf(A4, sW1[4 * 16 + f], h);
    float v = fmaxf(fmaf(di, h, sb1[f]), 0.f);
    o = fmaf(v, sW2[f], o);
  }
  o += __shfl_xor(o, 1);
  o += __shfl_xor(o, 2);
  if (l4 == 0) z[node] = di * o;
}

// ---- pass 4: layer-2 — atomic-free segmented gather of scalar z ------------
__global__ void __launch_bounds__(1024) k_agg2(const int* __restrict__ bins,
                                               const int* __restrict__ roff,
                                               const float* __restrict__ z,
                                               const float* __restrict__ dinv,
                                               const float* __restrict__ b2,
                                               float* __restrict__ out, int n) {
  int t = threadIdx.x;
  int g = t >> 2, l4 = t & 3;
  int b = blockIdx.x;
  int node = b * RANGE + g;
  if (node >= n) return;
  int r0 = roff[b * (RANGE + 1) + g];
  int r1 = roff[b * (RANGE + 1) + g + 1];
  float a = 0.f;
  for (int k = r0 + l4; k < r1; k += 4) a += z[bins[k] & 0xFFFFFF];
  a += __shfl_xor(a, 1);
  a += __shfl_xor(a, 2);
  if (l4 == 0) out[node] = fmaf(dinv[node], a + z[node], b2[0]);
}

extern "C" void kernel_launch(void* const* d_in, const int* in_sizes, int n_in,
                              void* d_out, int out_size, void* d_ws, size_t ws_size,
                              hipStream_t stream) {
  const float* x  = (const float*)d_in[0];
  const float* W1 = (const float*)d_in[1];
  const float* b1 = (const float*)d_in[2];
  const float* W2 = (const float*)d_in[3];
  const float* b2 = (const float*)d_in[4];
  const int*   ei = (const int*)d_in[5];

  int n = in_sizes[0] / 5;
  int e = in_sizes[5] / 2;
  const int* src = ei;
  const int* dst = ei + e;
  int nb = (n + RANGE - 1) / RANGE;  // 391

  char* ws = (char*)d_ws;
  int*   bins   = (int*)ws;   ws += (size_t)nb * CAP * sizeof(int);
  float* y      = (float*)ws; ws += (size_t)nb * RANGE * 8 * sizeof(float);
  float* dinv   = (float*)ws; ws += (size_t)n * sizeof(float);
  float* z      = (float*)ws; ws += (size_t)n * sizeof(float);
  int*   cursor = (int*)ws;   ws += (size_t)nb * sizeof(int);
  int*   roff   = (int*)ws;   ws += (size_t)nb * (RANGE + 1) * sizeof(int);

  float* out = (float*)d_out;

  int chunks = (e + CHUNK - 1) / CHUNK;

  k_init<<<(nb + 255) / 256, 256, 0, stream>>>(cursor, nb);
  k_place<<<chunks, 256, 0, stream>>>(src, dst, cursor, bins, e, nb);
  k_sortbin<<<nb, 1024, 0, stream>>>(bins, cursor, x, dinv, y, roff, n);
  k_agg1<<<nb, 1024, 0, stream>>>(bins, roff, y, dinv, W1, b1, W2, z, n);
  k_agg2<<<nb, 1024, 0, stream>>>(bins, roff, z, dinv, b2, out, n);
}

// Round 8
// 138.220 us; speedup vs baseline: 1.0604x; 1.0026x over previous
//
#include <hip/hip_runtime.h>

// 2-layer GCN, N=100000 (F0=5, F1=16, F2=1), E=3200000.
// place (LDS counting-sort to 256-node bins) -> per-QUARTER ballot radix sort
// (atomic-free, 256-thread blocks) -> atomic-free segmented-gather aggregation.
//   bin b owns nodes [b*256, b*256+256) at bins[b*CAP ...]; entry = (dst&255)<<24 | src.
//   Each bin's edge run is split into 4 quarters; each quarter sorted by dl
//   independently ->每node has 4 runs; agg lane q walks run q.
//   y[i]   = dinv[i]*x[i] (5 floats padded to 8)
//   z[i]   = dinv[i]*(relu(dinv[i]*(sum y[s] + y[i])@W1 + b1)@W2)
//   out[i] = dinv[i]*(sum z[s] + z[i]) + b2

constexpr int CHUNK = 4096;        // edges per k_place block
constexpr int RANGE = 256;         // nodes per bin
constexpr int CAP   = 12288;       // slots per bin region (max bin ~8.6K)
constexpr int QCAP  = CAP / 4;     // 3072 slots per quarter
constexpr int NQ    = QCAP / 256;  // 12 iters max per quarter block

__global__ void k_init(int* __restrict__ cursor, int nb) {
  int b = blockIdx.x * blockDim.x + threadIdx.x;
  if (b < nb) cursor[b] = b * CAP;
}

// ---- pass 1: LDS counting-sort each chunk into bin regions (coalesced) -----
__global__ void __launch_bounds__(256) k_place(const int* __restrict__ src,
                                               const int* __restrict__ dst,
                                               int* __restrict__ cursor,
                                               int* __restrict__ bins,
                                               int e, int nb) {
  __shared__ int entry4[CHUNK];
  __shared__ short bin2[CHUNK];
  __shared__ int hist[512], scan[512], lofs[512], base[512], pcur[512];
  int t = threadIdx.x;
  int e0 = blockIdx.x * CHUNK;
  int cnt = e - e0; if (cnt > CHUNK) cnt = CHUNK;

  for (int b = t; b < 512; b += 256) hist[b] = 0;
  __syncthreads();
  for (int i = t; i < cnt; i += 256) atomicAdd(&hist[dst[e0 + i] >> 8], 1);
  __syncthreads();
  scan[t] = hist[t]; scan[t + 256] = hist[t + 256];
  __syncthreads();
  for (int d = 1; d < 512; d <<= 1) {
    int v0 = (t >= d) ? scan[t - d] : 0;
    int v1 = (t + 256 >= d) ? scan[t + 256 - d] : 0;
    __syncthreads();
    scan[t] += v0; scan[t + 256] += v1;
    __syncthreads();
  }
  for (int b = t; b < 512; b += 256) {
    int lo = scan[b] - hist[b];
    lofs[b] = lo;
    pcur[b] = lo;
    if (b < nb && hist[b]) base[b] = atomicAdd(&cursor[b], hist[b]);  // absolute
  }
  __syncthreads();
  for (int i = t; i < cnt; i += 256) {
    int d = dst[e0 + i];
    int b = d >> 8;
    int slot = atomicAdd(&pcur[b], 1);
    entry4[slot] = ((d & 255) << 24) | src[e0 + i];
    bin2[slot] = (short)b;
  }
  __syncthreads();
  for (int i = t; i < cnt; i += 256) {
    int b = bin2[i];
    bins[base[b] + (i - lofs[b])] = entry4[i];
  }
}

// 64-lane match mask for a 4-bit digit (lanes with a==false excluded).
__device__ inline unsigned long long match4(bool a, int d) {
  unsigned long long m = __ballot(a);
#pragma unroll
  for (int bit = 0; bit < 4; ++bit) {
    unsigned long long bb = __ballot(a && ((d >> bit) & 1));
    m &= ((d >> bit) & 1) ? bb : ~bb;
  }
  return m;
}

// ---- pass 2: per-QUARTER in-place ballot radix sort (2x4-bit LSD) ----------
// grid = nb*4 blocks of 256 threads; block (b,q) sorts quarter q of bin b.
__global__ void __launch_bounds__(256) k_qsort(int* __restrict__ bins,
                                               const int* __restrict__ cursor,
                                               int* __restrict__ roff, int nb) {
  __shared__ int A[QCAP];            // 12 KB
  __shared__ int vcnt[NQ * 4][16];   // 3 KB  [row][digit]
  __shared__ int ssum[16][16];       // [digit][chunk]
  __shared__ int dtot[16];
  __shared__ int dbase[17];

  const int t = threadIdx.x;
  const int lane = t & 63, w = t >> 6;   // 4 waves
  const int bq = blockIdx.x;
  const int b = bq >> 2, q = bq & 3;
  const int bse = b * CAP;
  const int len = cursor[b] - bse;
  const int s0 = (len * q) >> 2, s1 = (len * (q + 1)) >> 2;
  const int L = s1 - s0;
  const int gbase = bse + s0;
  const int nIter = (L + 255) >> 8;
  const unsigned long long low = (1ull << lane) - 1ull;

  unsigned ev[NQ];

  // ======================= PASS 1: digit = bits 24..27 ======================
#pragma unroll
  for (int i = 0; i < NQ; ++i) {
    int k = (i << 8) + t;
    ev[i] = (i < nIter && k < L) ? (unsigned)bins[gbase + k] : 0u;
  }
  for (int j = t; j < NQ * 4 * 16; j += 256) ((int*)vcnt)[j] = 0;
  __syncthreads();
#pragma unroll
  for (int i = 0; i < NQ; ++i) if (i < nIter) {
    bool a = ((i << 8) + t) < L;
    int d = (ev[i] >> 24) & 15;
    unsigned long long m = match4(a, d);
    if (a && (m & low) == 0) vcnt[(i << 2) + w][d] = __popcll(m);
  }
  __syncthreads();
  {  // scan vcnt rows per digit (V rows), then digit bases
    const int V = NQ * 4;      // scan full array (zeros beyond nIter*4 harmless)
    if (t < 256) {
      int d = t & 15, c = t >> 4;          // 16 chunks of 3 rows
      int r0 = c * 3, r1 = r0 + 3;
      int s = 0;
      for (int r = r0; r < r1 && r < V; ++r) { int v = vcnt[r][d]; vcnt[r][d] = s; s += v; }
      ssum[d][c] = s;
    }
    __syncthreads();
    if (t < 16) {
      int run = 0;
      for (int c = 0; c < 16; ++c) { int v = ssum[t][c]; ssum[t][c] = run; run += v; }
      dtot[t] = run;
    }
    __syncthreads();
    if (t == 0) {
      int run = 0;
      for (int d = 0; d < 16; ++d) { dbase[d] = run; run += dtot[d]; }
      dbase[16] = run;
    }
    if (t < 256) {
      int d = t & 15, c = t >> 4;
      int add = ssum[d][c];
      int r0 = c * 3, r1 = r0 + 3;
      for (int r = r0; r < r1 && r < V; ++r) vcnt[r][d] += add;
    }
    __syncthreads();
  }
#pragma unroll
  for (int i = 0; i < NQ; ++i) if (i < nIter) {
    bool a = ((i << 8) + t) < L;
    int d = (ev[i] >> 24) & 15;
    unsigned long long m = match4(a, d);
    if (a) {
      int rank = __popcll(m & low);
      A[dbase[d] + vcnt[(i << 2) + w][d] + rank] = (int)ev[i];
    }
  }
  __syncthreads();

  // ======================= PASS 2: digit = bits 28..31 (stable) =============
#pragma unroll
  for (int i = 0; i < NQ; ++i) {
    int k = (i << 8) + t;
    ev[i] = (i < nIter && k < L) ? (unsigned)A[k] : 0u;
  }
  for (int j = t; j < NQ * 4 * 16; j += 256) ((int*)vcnt)[j] = 0;
  __syncthreads();
#pragma unroll
  for (int i = 0; i < NQ; ++i) if (i < nIter) {
    bool a = ((i << 8) + t) < L;
    int d = ev[i] >> 28;
    unsigned long long m = match4(a, d);
    if (a && (m & low) == 0) vcnt[(i << 2) + w][d] = __popcll(m);
  }
  __syncthreads();
  {
    const int V = NQ * 4;
    if (t < 256) {
      int d = t & 15, c = t >> 4;
      int r0 = c * 3, r1 = r0 + 3;
      int s = 0;
      for (int r = r0; r < r1 && r < V; ++r) { int v = vcnt[r][d]; vcnt[r][d] = s; s += v; }
      ssum[d][c] = s;
    }
    __syncthreads();
    if (t < 16) {
      int run = 0;
      for (int c = 0; c < 16; ++c) { int v = ssum[t][c]; ssum[t][c] = run; run += v; }
      dtot[t] = run;
    }
    __syncthreads();
    if (t == 0) {
      int run = 0;
      for (int d = 0; d < 16; ++d) { dbase[d] = run; run += dtot[d]; }
      dbase[16] = run;
    }
    if (t < 256) {
      int d = t & 15, c = t >> 4;
      int add = ssum[d][c];
      int r0 = c * 3, r1 = r0 + 3;
      for (int r = r0; r < r1 && r < V; ++r) vcnt[r][d] += add;
    }
    __syncthreads();
  }
#pragma unroll
  for (int i = 0; i < NQ; ++i) if (i < nIter) {
    bool a = ((i << 8) + t) < L;
    int d = ev[i] >> 28;
    unsigned long long m = match4(a, d);
    if (a) {
      int rank = __popcll(m & low);
      A[dbase[d] + vcnt[(i << 2) + w][d] + rank] = (int)ev[i];
    }
  }
  __syncthreads();

  // ---- per-node run offsets within this quarter (binary search), writeback --
  {
    int lo = 0, hi = L;  // first index with dl >= t
    while (lo < hi) {
      int mid = (lo + hi) >> 1;
      int dl = ((unsigned)A[mid]) >> 24;
      if (dl < t) lo = mid + 1; else hi = mid;
    }
    roff[bq * (RANGE + 1) + t] = gbase + lo;
    if (t == 0) roff[bq * (RANGE + 1) + RANGE] = gbase + L;
  }
  for (int k = t; k < L; k += 256) bins[gbase + k] = A[k];
}

// ---- pass 3: per-node degree from 4 quarter runs; dinv; y = dinv*x ---------
__global__ void __launch_bounds__(256) k_nodey(const int* __restrict__ roff,
                                               const float* __restrict__ x,
                                               float* __restrict__ dinv,
                                               float* __restrict__ y, int n) {
  int t = threadIdx.x;
  int b = blockIdx.x;
  int node = b * RANGE + t;
  if (node >= n) return;
  int deg = 0;
#pragma unroll
  for (int q = 0; q < 4; ++q) {
    const int* r = roff + (b * 4 + q) * (RANGE + 1);
    deg += r[t + 1] - r[t];
  }
  float dv = rsqrtf((float)(deg + 1));
  dinv[node] = dv;
  float4 a, c;
  a.x = dv * x[node * 5 + 0];
  a.y = dv * x[node * 5 + 1];
  a.z = dv * x[node * 5 + 2];
  a.w = dv * x[node * 5 + 3];
  c.x = dv * x[node * 5 + 4];
  c.y = c.z = c.w = 0.f;
  ((float4*)y)[(size_t)node * 2 + 0] = a;
  ((float4*)y)[(size_t)node * 2 + 1] = c;
}

// ---- pass 4: layer-1 — lane q walks quarter-q run; fused W1/relu/W2 --------
__global__ void __launch_bounds__(1024) k_agg1(const int* __restrict__ bins,
                                               const int* __restrict__ roff,
                                               const float* __restrict__ y,
                                               const float* __restrict__ dinv,
                                               const float* __restrict__ W1,
                                               const float* __restrict__ b1,
                                               const float* __restrict__ W2,
                                               float* __restrict__ z, int n) {
  __shared__ float sW1[80], sb1[16], sW2[16];
  int t = threadIdx.x;
  if (t < 80) sW1[t] = W1[t];
  else if (t < 96) sb1[t - 80] = b1[t - 80];
  else if (t < 112) sW2[t - 96] = W2[t - 96];
  __syncthreads();
  int g = t >> 2, l4 = t & 3;
  int b = blockIdx.x;
  int node = b * RANGE + g;
  if (node >= n) return;
  const int* r = roff + (b * 4 + l4) * (RANGE + 1);
  int r0 = r[g], r1 = r[g + 1];
  float a0 = 0.f, a1 = 0.f, a2 = 0.f, a3 = 0.f, a4 = 0.f;
  for (int k = r0; k < r1; ++k) {
    int s = bins[k] & 0xFFFFFF;
    float4 v = ((const float4*)y)[(size_t)s * 2];
    float v4 = y[(size_t)s * 8 + 4];
    a0 += v.x; a1 += v.y; a2 += v.z; a3 += v.w; a4 += v4;
  }
  a0 += __shfl_xor(a0, 1); a0 += __shfl_xor(a0, 2);
  a1 += __shfl_xor(a1, 1); a1 += __shfl_xor(a1, 2);
  a2 += __shfl_xor(a2, 1); a2 += __shfl_xor(a2, 2);
  a3 += __shfl_xor(a3, 1); a3 += __shfl_xor(a3, 2);
  a4 += __shfl_xor(a4, 1); a4 += __shfl_xor(a4, 2);
  float4 ys = ((const float4*)y)[(size_t)node * 2];
  float ys4 = y[(size_t)node * 8 + 4];
  float A0 = a0 + ys.x, A1 = a1 + ys.y, A2 = a2 + ys.z, A3 = a3 + ys.w, A4 = a4 + ys4;
  float di = dinv[node];
  float o = 0.f;
#pragma unroll
  for (int fi = 0; fi < 4; ++fi) {
    int f = l4 * 4 + fi;
    float h = A0 * sW1[0 * 16 + f];
    h = fmaf(A1, sW1[1 * 16 + f], h);
    h = fmaf(A2, sW1[2 * 16 + f], h);
    h = fmaf(A3, sW1[3 * 16 + f], h);
    h = fmaf(A4, sW1[4 * 16 + f], h);
    float v = fmaxf(fmaf(di, h, sb1[f]), 0.f);
    o = fmaf(v, sW2[f], o);
  }
  o += __shfl_xor(o, 1);
  o += __shfl_xor(o, 2);
  if (l4 == 0) z[node] = di * o;
}

// ---- pass 5: layer-2 — lane q walks quarter-q run; scalar z gather ---------
__global__ void __launch_bounds__(1024) k_agg2(const int* __restrict__ bins,
                                               const int* __restrict__ roff,
                                               const float* __restrict__ z,
                                               const float* __restrict__ dinv,
                                               const float* __restrict__ b2,
                                               float* __restrict__ out, int n) {
  int t = threadIdx.x;
  int g = t >> 2, l4 = t & 3;
  int b = blockIdx.x;
  int node = b * RANGE + g;
  if (node >= n) return;
  const int* r = roff + (b * 4 + l4) * (RANGE + 1);
  int r0 = r[g], r1 = r[g + 1];
  float a = 0.f;
  for (int k = r0; k < r1; ++k) a += z[bins[k] & 0xFFFFFF];
  a += __shfl_xor(a, 1);
  a += __shfl_xor(a, 2);
  if (l4 == 0) out[node] = fmaf(dinv[node], a + z[node], b2[0]);
}

extern "C" void kernel_launch(void* const* d_in, const int* in_sizes, int n_in,
                              void* d_out, int out_size, void* d_ws, size_t ws_size,
                              hipStream_t stream) {
  const float* x  = (const float*)d_in[0];
  const float* W1 = (const float*)d_in[1];
  const float* b1 = (const float*)d_in[2];
  const float* W2 = (const float*)d_in[3];
  const float* b2 = (const float*)d_in[4];
  const int*   ei = (const int*)d_in[5];

  int n = in_sizes[0] / 5;
  int e = in_sizes[5] / 2;
  const int* src = ei;
  const int* dst = ei + e;
  int nb = (n + RANGE - 1) / RANGE;  // 391

  char* ws = (char*)d_ws;
  int*   bins   = (int*)ws;   ws += (size_t)nb * CAP * sizeof(int);
  float* y      = (float*)ws; ws += (size_t)nb * RANGE * 8 * sizeof(float);
  float* dinv   = (float*)ws; ws += (size_t)n * sizeof(float);
  float* z      = (float*)ws; ws += (size_t)n * sizeof(float);
  int*   cursor = (int*)ws;   ws += (size_t)nb * sizeof(int);
  int*   roff   = (int*)ws;   ws += (size_t)nb * 4 * (RANGE + 1) * sizeof(int);

  float* out = (float*)d_out;

  int chunks = (e + CHUNK - 1) / CHUNK;

  k_init<<<(nb + 255) / 256, 256, 0, stream>>>(cursor, nb);
  k_place<<<chunks, 256, 0, stream>>>(src, dst, cursor, bins, e, nb);
  k_qsort<<<nb * 4, 256, 0, stream>>>(bins, cursor, roff, nb);
  k_nodey<<<nb, 256, 0, stream>>>(roff, x, dinv, y, n);
  k_agg1<<<nb, 1024, 0, stream>>>(bins, roff, y, dinv, W1, b1, W2, z, n);
  k_agg2<<<nb, 1024, 0, stream>>>(bins, roff, z, dinv, b2, out, n);
}

// Round 9
// 124.859 us; speedup vs baseline: 1.1739x; 1.1070x over previous
//
#include <hip/hip_runtime.h>

// 2-layer GCN, N=100000 (F0=5, F1=16, F2=1), E=3200000.
// Round-5 structure (best measured: 109.9us) with a 1-LDS-atomic k_place:
//   k_place: per-bin fixed-cap LDS lists (1 atomic/edge) + scan + binary-search
//            compacted coalesced write-out; rare overflow spills via global cursor.
//   k_sortbin: per-bin LDS counting sort by dl (atomic), roff runs, dinv, y.
//   k_agg1/k_agg2: atomic-free segmented gathers.
//   y[i]   = dinv[i]*x[i] (5 floats padded to 8)
//   z[i]   = dinv[i]*(relu(dinv[i]*(sum_run y[s] + y[i])@W1 + b1)@W2)
//   out[i] = dinv[i]*(sum_run z[s] + z[i]) + b2

constexpr int CHUNK = 4096;   // edges per k_place block
constexpr int RANGE = 256;    // nodes per bin
constexpr int CAP   = 12288;  // slots per bin region (max bin ~8.6K)
constexpr int NBIN  = 392;    // bins (=ceil(100000/256)+1 pad)
constexpr int LCAP  = 28;     // per-bin LDS list capacity (lambda=10.45)

__global__ void k_init(int* __restrict__ cursor, int nb) {
  int b = blockIdx.x * blockDim.x + threadIdx.x;
  if (b < nb) cursor[b] = b * CAP;
}

// ---- pass 1: 1-atomic chunk binning with compacted coalesced write-out -----
__global__ void __launch_bounds__(256) k_place(const int* __restrict__ src,
                                               const int* __restrict__ dst,
                                               int* __restrict__ cursor,
                                               int* __restrict__ bins,
                                               int e, int nb) {
  __shared__ int lists[NBIN * LCAP];   // 43.9 KB
  __shared__ int pcur[NBIN];
  __shared__ int sI[512];              // inclusive scan of counts (padded)
  __shared__ int base[NBIN];
  int t = threadIdx.x;
  int e0 = blockIdx.x * CHUNK;
  int cnt = e - e0; if (cnt > CHUNK) cnt = CHUNK;

  for (int b = t; b < NBIN; b += 256) pcur[b] = 0;
  __syncthreads();

  // phase A: direct scatter into per-bin LDS lists (1 LDS atomic per edge)
  for (int i = t; i < cnt; i += 256) {
    int d = dst[e0 + i];
    int s = src[e0 + i];
    int b = d >> 8;
    int entry = ((d & 255) << 24) | s;
    int slot = atomicAdd(&pcur[b], 1);
    if (slot < LCAP) lists[b * LCAP + slot] = entry;
    else bins[atomicAdd(&cursor[b], 1)] = entry;  // rare spill (P ~ 5e-9)
  }
  __syncthreads();

  // phase B: inclusive scan of clamped counts; reserve global runs
  {
    int c0 = (t < NBIN) ? min(pcur[t], LCAP) : 0;
    int t2 = t + 256;
    int c1 = (t2 < NBIN) ? min(pcur[t2], LCAP) : 0;
    sI[t] = c0; sI[t2] = c1;
    __syncthreads();
    for (int d = 1; d < 512; d <<= 1) {
      int v0 = (t >= d) ? sI[t - d] : 0;
      int v1 = (t2 >= d) ? sI[t2 - d] : 0;
      __syncthreads();
      sI[t] += v0; sI[t2] += v1;
      __syncthreads();
    }
    if (t < NBIN && c0) base[t] = atomicAdd(&cursor[t], c0);
    if (t2 < NBIN && c1) base[t2] = atomicAdd(&cursor[t2], c1);
  }
  __syncthreads();

  // phase C: compacted write-out; j-consecutive -> coalesced global writes
  int T = sI[NBIN - 1];
  for (int j = t; j < T; j += 256) {
    // smallest b with sI[b] > j  (9-step binary search, wave-parallel LDS reads)
    int lo = 0, hi = NBIN - 1;
    while (lo < hi) {
      int mid = (lo + hi) >> 1;
      if (sI[mid] > j) hi = mid; else lo = mid + 1;
    }
    int b = lo;
    int excl = sI[b] - min(pcur[b], LCAP);
    int local = j - excl;
    bins[base[b] + local] = lists[b * LCAP + local];
  }
}

// ---- pass 2: per-bin counting sort by dl; emit run offsets, deg->dinv, y ----
__global__ void __launch_bounds__(1024) k_sortbin(int* __restrict__ bins,
                                                  const int* __restrict__ cursor,
                                                  const float* __restrict__ x,
                                                  float* __restrict__ dinv,
                                                  float* __restrict__ y,
                                                  int* __restrict__ roff, int n) {
  __shared__ int sorted[CAP];
  __shared__ int hist[RANGE], sc[RANGE], pcur[RANGE];
  int t = threadIdx.x;
  int b = blockIdx.x;
  int bse = b * CAP;
  int len = cursor[b] - bse;
  if (t < RANGE) hist[t] = 0;
  __syncthreads();
  for (int k = t; k < len; k += 1024)
    atomicAdd(&hist[((unsigned)bins[bse + k]) >> 24], 1);
  __syncthreads();
  if (t < RANGE) sc[t] = hist[t];
  __syncthreads();
  for (int d = 1; d < RANGE; d <<= 1) {
    int v = 0;
    if (t < RANGE && t >= d) v = sc[t - d];
    __syncthreads();
    if (t < RANGE) sc[t] += v;
    __syncthreads();
  }
  if (t < RANGE) pcur[t] = sc[t] - hist[t];
  __syncthreads();
  for (int k = t; k < len; k += 1024) {
    unsigned e4 = (unsigned)bins[bse + k];
    int slot = atomicAdd(&pcur[e4 >> 24], 1);
    sorted[slot] = (int)(e4 & 0xFFFFFF);
  }
  __syncthreads();
  for (int k = t; k < len; k += 1024) bins[bse + k] = sorted[k];
  if (t < RANGE) roff[b * (RANGE + 1) + t] = bse + sc[t] - hist[t];
  if (t == 0) roff[b * (RANGE + 1) + RANGE] = bse + len;
  if (t < RANGE) {
    int node = b * RANGE + t;
    if (node < n) {
      float dv = rsqrtf((float)(hist[t] + 1));
      dinv[node] = dv;
      float4 a, c;
      a.x = dv * x[node * 5 + 0];
      a.y = dv * x[node * 5 + 1];
      a.z = dv * x[node * 5 + 2];
      a.w = dv * x[node * 5 + 3];
      c.x = dv * x[node * 5 + 4];
      c.y = c.z = c.w = 0.f;
      ((float4*)y)[(size_t)node * 2 + 0] = a;
      ((float4*)y)[(size_t)node * 2 + 1] = c;
    }
  }
}

// ---- pass 3: layer-1 — atomic-free segmented gather + fused W1/relu/W2 -----
__global__ void __launch_bounds__(1024) k_agg1(const int* __restrict__ bins,
                                               const int* __restrict__ roff,
                                               const float* __restrict__ y,
                                               const float* __restrict__ dinv,
                                               const float* __restrict__ W1,
                                               const float* __restrict__ b1,
                                               const float* __restrict__ W2,
                                               float* __restrict__ z, int n) {
  __shared__ float sW1[80], sb1[16], sW2[16];
  int t = threadIdx.x;
  if (t < 80) sW1[t] = W1[t];
  else if (t < 96) sb1[t - 80] = b1[t - 80];
  else if (t < 112) sW2[t - 96] = W2[t - 96];
  __syncthreads();
  int g = t >> 2, l4 = t & 3;
  int b = blockIdx.x;
  int node = b * RANGE + g;
  if (node >= n) return;
  int r0 = roff[b * (RANGE + 1) + g];
  int r1 = roff[b * (RANGE + 1) + g + 1];
  float a0 = 0.f, a1 = 0.f, a2 = 0.f, a3 = 0.f, a4 = 0.f;
  for (int k = r0 + l4; k < r1; k += 4) {
    int s = bins[k];
    float4 v = ((const float4*)y)[(size_t)s * 2];
    float v4 = y[(size_t)s * 8 + 4];
    a0 += v.x; a1 += v.y; a2 += v.z; a3 += v.w; a4 += v4;
  }
  a0 += __shfl_xor(a0, 1); a0 += __shfl_xor(a0, 2);
  a1 += __shfl_xor(a1, 1); a1 += __shfl_xor(a1, 2);
  a2 += __shfl_xor(a2, 1); a2 += __shfl_xor(a2, 2);
  a3 += __shfl_xor(a3, 1); a3 += __shfl_xor(a3, 2);
  a4 += __shfl_xor(a4, 1); a4 += __shfl_xor(a4, 2);
  float4 ys = ((const float4*)y)[(size_t)node * 2];
  float ys4 = y[(size_t)node * 8 + 4];
  float A0 = a0 + ys.x, A1 = a1 + ys.y, A2 = a2 + ys.z, A3 = a3 + ys.w, A4 = a4 + ys4;
  float di = dinv[node];
  float o = 0.f;
#pragma unroll
  for (int fi = 0; fi < 4; ++fi) {
    int f = l4 * 4 + fi;
    float h = A0 * sW1[0 * 16 + f];
    h = fmaf(A1, sW1[1 * 16 + f], h);
    h = fmaf(A2, sW1[2 * 16 + f], h);
    h = fmaf(A3, sW1[3 * 16 + f], h);
    h = fmaf(A4, sW1[4 * 16 + f], h);
    float v = fmaxf(fmaf(di, h, sb1[f]), 0.f);
    o = fmaf(v, sW2[f], o);
  }
  o += __shfl_xor(o, 1);
  o += __shfl_xor(o, 2);
  if (l4 == 0) z[node] = di * o;
}

// ---- pass 4: layer-2 — atomic-free segmented gather of scalar z ------------
__global__ void __launch_bounds__(1024) k_agg2(const int* __restrict__ bins,
                                               const int* __restrict__ roff,
                                               const float* __restrict__ z,
                                               const float* __restrict__ dinv,
                                               const float* __restrict__ b2,
                                               float* __restrict__ out, int n) {
  int t = threadIdx.x;
  int g = t >> 2, l4 = t & 3;
  int b = blockIdx.x;
  int node = b * RANGE + g;
  if (node >= n) return;
  int r0 = roff[b * (RANGE + 1) + g];
  int r1 = roff[b * (RANGE + 1) + g + 1];
  float a = 0.f;
  for (int k = r0 + l4; k < r1; k += 4) a += z[bins[k]];
  a += __shfl_xor(a, 1);
  a += __shfl_xor(a, 2);
  if (l4 == 0) out[node] = fmaf(dinv[node], a + z[node], b2[0]);
}

extern "C" void kernel_launch(void* const* d_in, const int* in_sizes, int n_in,
                              void* d_out, int out_size, void* d_ws, size_t ws_size,
                              hipStream_t stream) {
  const float* x  = (const float*)d_in[0];
  const float* W1 = (const float*)d_in[1];
  const float* b1 = (const float*)d_in[2];
  const float* W2 = (const float*)d_in[3];
  const float* b2 = (const float*)d_in[4];
  const int*   ei = (const int*)d_in[5];

  int n = in_sizes[0] / 5;
  int e = in_sizes[5] / 2;
  const int* src = ei;
  const int* dst = ei + e;
  int nb = (n + RANGE - 1) / RANGE;  // 391

  char* ws = (char*)d_ws;
  int*   bins   = (int*)ws;   ws += (size_t)nb * CAP * sizeof(int);
  float* y      = (float*)ws; ws += (size_t)nb * RANGE * 8 * sizeof(float);
  float* dinv   = (float*)ws; ws += (size_t)n * sizeof(float);
  float* z      = (float*)ws; ws += (size_t)n * sizeof(float);
  int*   cursor = (int*)ws;   ws += (size_t)nb * sizeof(int);
  int*   roff   = (int*)ws;   ws += (size_t)nb * (RANGE + 1) * sizeof(int);

  float* out = (float*)d_out;

  int chunks = (e + CHUNK - 1) / CHUNK;

  k_init<<<(nb + 255) / 256, 256, 0, stream>>>(cursor, nb);
  k_place<<<chunks, 256, 0, stream>>>(src, dst, cursor, bins, e, nb);
  k_sortbin<<<nb, 1024, 0, stream>>>(bins, cursor, x, dinv, y, roff, n);
  k_agg1<<<nb, 1024, 0, stream>>>(bins, roff, y, dinv, W1, b1, W2, z, n);
  k_agg2<<<nb, 1024, 0, stream>>>(bins, roff, z, dinv, b2, out, n);
}

// Round 10
// 122.898 us; speedup vs baseline: 1.1926x; 1.0160x over previous
//
#include <hip/hip_runtime.h>

// 2-layer GCN, N=100000 (F0=5, F1=16, F2=1), E=3200000.
// Round-5 structure (best measured: 109.9us) with ONE change: k_sortbin's
// histogram phase is ballot-based (non-atomic), cutting sortbin to 1 LDS
// atomic per edge (the scatter cursor). Everything else identical to round 5.
//   bin b owns nodes [b*256, b*256+256) at bins[b*CAP ...]; entry = (dst&255)<<24 | src.
//   y[i]   = dinv[i]*x[i] (5 floats padded to 8)
//   z[i]   = dinv[i]*(relu(dinv[i]*(sum_run y[s] + y[i])@W1 + b1)@W2)
//   out[i] = dinv[i]*(sum_run z[s] + z[i]) + b2

constexpr int CHUNK = 4096;        // edges per k_place block
constexpr int RANGE = 256;         // nodes per bin
constexpr int CAP   = 12288;       // slots per bin region (max bin ~8.6K)
constexpr int NITER = CAP / 1024;  // 12 register-prefetch slots

__global__ void k_init(int* __restrict__ cursor, int nb) {
  int b = blockIdx.x * blockDim.x + threadIdx.x;
  if (b < nb) cursor[b] = b * CAP;
}

// ---- pass 1: LDS counting-sort each chunk into bin regions (round-5) -------
__global__ void __launch_bounds__(256) k_place(const int* __restrict__ src,
                                               const int* __restrict__ dst,
                                               int* __restrict__ cursor,
                                               int* __restrict__ bins,
                                               int e, int nb) {
  __shared__ int entry4[CHUNK];
  __shared__ short bin2[CHUNK];
  __shared__ int hist[512], scan[512], lofs[512], base[512], pcur[512];
  int t = threadIdx.x;
  int e0 = blockIdx.x * CHUNK;
  int cnt = e - e0; if (cnt > CHUNK) cnt = CHUNK;

  for (int b = t; b < 512; b += 256) hist[b] = 0;
  __syncthreads();
  for (int i = t; i < cnt; i += 256) atomicAdd(&hist[dst[e0 + i] >> 8], 1);
  __syncthreads();
  scan[t] = hist[t]; scan[t + 256] = hist[t + 256];
  __syncthreads();
  for (int d = 1; d < 512; d <<= 1) {
    int v0 = (t >= d) ? scan[t - d] : 0;
    int v1 = (t + 256 >= d) ? scan[t + 256 - d] : 0;
    __syncthreads();
    scan[t] += v0; scan[t + 256] += v1;
    __syncthreads();
  }
  for (int b = t; b < 512; b += 256) {
    int lo = scan[b] - hist[b];
    lofs[b] = lo;
    pcur[b] = lo;
    if (b < nb && hist[b]) base[b] = atomicAdd(&cursor[b], hist[b]);  // absolute
  }
  __syncthreads();
  for (int i = t; i < cnt; i += 256) {
    int d = dst[e0 + i];
    int b = d >> 8;
    int slot = atomicAdd(&pcur[b], 1);
    entry4[slot] = ((d & 255) << 24) | src[e0 + i];
    bin2[slot] = (short)b;
  }
  __syncthreads();
  for (int i = t; i < cnt; i += 256) {
    int b = bin2[i];
    bins[base[b] + (i - lofs[b])] = entry4[i];
  }
}

// ---- pass 2: per-bin counting sort; ballot hist (no atomic) + 1-atomic scatter
__global__ void __launch_bounds__(1024) k_sortbin(int* __restrict__ bins,
                                                  const int* __restrict__ cursor,
                                                  const float* __restrict__ x,
                                                  float* __restrict__ dinv,
                                                  float* __restrict__ y,
                                                  int* __restrict__ roff, int n) {
  __shared__ int sorted[CAP];        // 48 KB
  __shared__ int whist[16][RANGE];   // 16 KB per-wave histogram (non-atomic)
  __shared__ int hist[RANGE], sc[RANGE], pcur[RANGE];

  const int t = threadIdx.x;
  const int lane = t & 63, w = t >> 6;  // 16 waves
  const int b = blockIdx.x;
  const int bse = b * CAP;
  const int len = cursor[b] - bse;
  const int nIter = (len + 1023) >> 10;
  const unsigned long long low = (1ull << lane) - 1ull;

  unsigned ev[NITER];
#pragma unroll
  for (int i = 0; i < NITER; ++i) {  // prefetch global -> regs (read once)
    int k = (i << 10) + t;
    ev[i] = (i < nIter && k < len) ? (unsigned)bins[bse + k] : 0u;
  }
  for (int j = t; j < 16 * RANGE; j += 1024) ((int*)whist)[j] = 0;
  __syncthreads();

  // ballot histogram: full 8-bit match; wave leader does plain RMW (no atomic)
#pragma unroll
  for (int i = 0; i < NITER; ++i) if (i < nIter) {
    bool a = ((i << 10) + t) < len;
    int dl = (int)(ev[i] >> 24);
    unsigned long long m = __ballot(a);
#pragma unroll
    for (int bit = 0; bit < 8; ++bit) {
      unsigned long long bb = __ballot(a && ((dl >> bit) & 1));
      m &= ((dl >> bit) & 1) ? bb : ~bb;
    }
    if (a && (m & low) == 0)           // leader for this dl in this wave
      whist[w][dl] += __popcll(m);     // distinct addresses within wave: safe
  }
  __syncthreads();
  if (t < RANGE) {
    int s = 0;
#pragma unroll
    for (int j = 0; j < 16; ++j) s += whist[j][t];
    hist[t] = s;
    sc[t] = s;
  }
  __syncthreads();
  for (int d = 1; d < RANGE; d <<= 1) {
    int v = 0;
    if (t < RANGE && t >= d) v = sc[t - d];
    __syncthreads();
    if (t < RANGE) sc[t] += v;
    __syncthreads();
  }
  if (t < RANGE) pcur[t] = sc[t] - hist[t];
  __syncthreads();

  // scatter: single LDS atomic per edge
#pragma unroll
  for (int i = 0; i < NITER; ++i) if (i < nIter) {
    int k = (i << 10) + t;
    if (k < len) {
      unsigned e4 = ev[i];
      int slot = atomicAdd(&pcur[e4 >> 24], 1);
      sorted[slot] = (int)(e4 & 0xFFFFFF);
    }
  }
  __syncthreads();
  for (int k = t; k < len; k += 1024) bins[bse + k] = sorted[k];
  if (t < RANGE) roff[b * (RANGE + 1) + t] = bse + sc[t] - hist[t];
  if (t == 0) roff[b * (RANGE + 1) + RANGE] = bse + len;
  if (t < RANGE) {
    int node = b * RANGE + t;
    if (node < n) {
      float dv = rsqrtf((float)(hist[t] + 1));
      dinv[node] = dv;
      float4 a, c;
      a.x = dv * x[node * 5 + 0];
      a.y = dv * x[node * 5 + 1];
      a.z = dv * x[node * 5 + 2];
      a.w = dv * x[node * 5 + 3];
      c.x = dv * x[node * 5 + 4];
      c.y = c.z = c.w = 0.f;
      ((float4*)y)[(size_t)node * 2 + 0] = a;
      ((float4*)y)[(size_t)node * 2 + 1] = c;
    }
  }
}

// ---- pass 3: layer-1 — atomic-free segmented gather + fused W1/relu/W2 -----
__global__ void __launch_bounds__(1024) k_agg1(const int* __restrict__ bins,
                                               const int* __restrict__ roff,
                                               const float* __restrict__ y,
                                               const float* __restrict__ dinv,
                                               const float* __restrict__ W1,
                                               const float* __restrict__ b1,
                                               const float* __restrict__ W2,
                                               float* __restrict__ z, int n) {
  __shared__ float sW1[80], sb1[16], sW2[16];
  int t = threadIdx.x;
  if (t < 80) sW1[t] = W1[t];
  else if (t < 96) sb1[t - 80] = b1[t - 80];
  else if (t < 112) sW2[t - 96] = W2[t - 96];
  __syncthreads();
  int g = t >> 2, l4 = t & 3;
  int b = blockIdx.x;
  int node = b * RANGE + g;
  if (node >= n) return;
  int r0 = roff[b * (RANGE + 1) + g];
  int r1 = roff[b * (RANGE + 1) + g + 1];
  float a0 = 0.f, a1 = 0.f, a2 = 0.f, a3 = 0.f, a4 = 0.f;
  for (int k = r0 + l4; k < r1; k += 4) {
    int s = bins[k];
    float4 v = ((const float4*)y)[(size_t)s * 2];
    float v4 = y[(size_t)s * 8 + 4];
    a0 += v.x; a1 += v.y; a2 += v.z; a3 += v.w; a4 += v4;
  }
  a0 += __shfl_xor(a0, 1); a0 += __shfl_xor(a0, 2);
  a1 += __shfl_xor(a1, 1); a1 += __shfl_xor(a1, 2);
  a2 += __shfl_xor(a2, 1); a2 += __shfl_xor(a2, 2);
  a3 += __shfl_xor(a3, 1); a3 += __shfl_xor(a3, 2);
  a4 += __shfl_xor(a4, 1); a4 += __shfl_xor(a4, 2);
  float4 ys = ((const float4*)y)[(size_t)node * 2];
  float ys4 = y[(size_t)node * 8 + 4];
  float A0 = a0 + ys.x, A1 = a1 + ys.y, A2 = a2 + ys.z, A3 = a3 + ys.w, A4 = a4 + ys4;
  float di = dinv[node];
  float o = 0.f;
#pragma unroll
  for (int fi = 0; fi < 4; ++fi) {
    int f = l4 * 4 + fi;
    float h = A0 * sW1[0 * 16 + f];
    h = fmaf(A1, sW1[1 * 16 + f], h);
    h = fmaf(A2, sW1[2 * 16 + f], h);
    h = fmaf(A3, sW1[3 * 16 + f], h);
    h = fmaf(A4, sW1[4 * 16 + f], h);
    float v = fmaxf(fmaf(di, h, sb1[f]), 0.f);
    o = fmaf(v, sW2[f], o);
  }
  o += __shfl_xor(o, 1);
  o += __shfl_xor(o, 2);
  if (l4 == 0) z[node] = di * o;
}

// ---- pass 4: layer-2 — atomic-free segmented gather of scalar z ------------
__global__ void __launch_bounds__(1024) k_agg2(const int* __restrict__ bins,
                                               const int* __restrict__ roff,
                                               const float* __restrict__ z,
                                               const float* __restrict__ dinv,
                                               const float* __restrict__ b2,
                                               float* __restrict__ out, int n) {
  int t = threadIdx.x;
  int g = t >> 2, l4 = t & 3;
  int b = blockIdx.x;
  int node = b * RANGE + g;
  if (node >= n) return;
  int r0 = roff[b * (RANGE + 1) + g];
  int r1 = roff[b * (RANGE + 1) + g + 1];
  float a = 0.f;
  for (int k = r0 + l4; k < r1; k += 4) a += z[bins[k]];
  a += __shfl_xor(a, 1);
  a += __shfl_xor(a, 2);
  if (l4 == 0) out[node] = fmaf(dinv[node], a + z[node], b2[0]);
}

extern "C" void kernel_launch(void* const* d_in, const int* in_sizes, int n_in,
                              void* d_out, int out_size, void* d_ws, size_t ws_size,
                              hipStream_t stream) {
  const float* x  = (const float*)d_in[0];
  const float* W1 = (const float*)d_in[1];
  const float* b1 = (const float*)d_in[2];
  const float* W2 = (const float*)d_in[3];
  const float* b2 = (const float*)d_in[4];
  const int*   ei = (const int*)d_in[5];

  int n = in_sizes[0] / 5;
  int e = in_sizes[5] / 2;
  const int* src = ei;
  const int* dst = ei + e;
  int nb = (n + RANGE - 1) / RANGE;  // 391

  char* ws = (char*)d_ws;
  int*   bins   = (int*)ws;   ws += (size_t)nb * CAP * sizeof(int);
  float* y      = (float*)ws; ws += (size_t)nb * RANGE * 8 * sizeof(float);
  float* dinv   = (float*)ws; ws += (size_t)n * sizeof(float);
  float* z      = (float*)ws; ws += (size_t)n * sizeof(float);
  int*   cursor = (int*)ws;   ws += (size_t)nb * sizeof(int);
  int*   roff   = (int*)ws;   ws += (size_t)nb * (RANGE + 1) * sizeof(int);

  float* out = (float*)d_out;

  int chunks = (e + CHUNK - 1) / CHUNK;

  k_init<<<(nb + 255) / 256, 256, 0, stream>>>(cursor, nb);
  k_place<<<chunks, 256, 0, stream>>>(src, dst, cursor, bins, e, nb);
  k_sortbin<<<nb, 1024, 0, stream>>>(bins, cursor, x, dinv, y, roff, n);
  k_agg1<<<nb, 1024, 0, stream>>>(bins, roff, y, dinv, W1, b1, W2, z, n);
  k_agg2<<<nb, 1024, 0, stream>>>(bins, roff, z, dinv, b2, out, n);
}

// Round 11
// 110.479 us; speedup vs baseline: 1.3267x; 1.1124x over previous
//
#include <hip/hip_runtime.h>

// 2-layer GCN, N=100000 (F0=5, F1=16, F2=1), E=3200000.
// Round-5 configuration (best measured: 109.9us), restored exactly.
//   k_place:   LDS counting-sort of 4096-edge chunks into 256-node bin regions
//              (2 LDS atomics/edge), coalesced bin-run write-out.
//   k_sortbin: per-bin LDS counting sort by dl (2 LDS atomics/edge), emits
//              dst-sorted src lists + run offsets + deg->dinv + y = dinv*x.
//   k_agg1/2:  atomic-free segmented gathers (4 lanes/node, shfl_xor reduce).
//   y[i]   = dinv[i]*x[i] (5 floats padded to 8)
//   z[i]   = dinv[i]*(relu(dinv[i]*(sum_run y[s] + y[i])@W1 + b1)@W2)
//   out[i] = dinv[i]*(sum_run z[s] + z[i]) + b2
//
// Structural note (rounds 5-10): the pipeline is DS-atomic-pipe-bound at
// ~4 serialized LDS-atomic lane-ops/edge (~4.5 cy each, occupancy-insensitive).
// Ballot-radix / 1-atomic / ballot-hist replacements all measured equal or
// worse (122.9-146.6 vs 109.9): the VALU+LDS machinery that replaces an
// atomic costs as much as the atomic on random keys.

constexpr int CHUNK = 4096;   // edges per k_place block
constexpr int RANGE = 256;    // nodes per bin
constexpr int CAP   = 12288;  // slots per bin region (max bin ~8.6K)

__global__ void k_init(int* __restrict__ cursor, int nb) {
  int b = blockIdx.x * blockDim.x + threadIdx.x;
  if (b < nb) cursor[b] = b * CAP;
}

// ---- pass 1: LDS counting-sort each chunk into bin regions (coalesced) -----
__global__ void __launch_bounds__(256) k_place(const int* __restrict__ src,
                                               const int* __restrict__ dst,
                                               int* __restrict__ cursor,
                                               int* __restrict__ bins,
                                               int e, int nb) {
  __shared__ int entry4[CHUNK];
  __shared__ short bin2[CHUNK];
  __shared__ int hist[512], scan[512], lofs[512], base[512], pcur[512];
  int t = threadIdx.x;
  int e0 = blockIdx.x * CHUNK;
  int cnt = e - e0; if (cnt > CHUNK) cnt = CHUNK;

  for (int b = t; b < 512; b += 256) hist[b] = 0;
  __syncthreads();
  for (int i = t; i < cnt; i += 256) atomicAdd(&hist[dst[e0 + i] >> 8], 1);
  __syncthreads();
  scan[t] = hist[t]; scan[t + 256] = hist[t + 256];
  __syncthreads();
  for (int d = 1; d < 512; d <<= 1) {
    int v0 = (t >= d) ? scan[t - d] : 0;
    int v1 = (t + 256 >= d) ? scan[t + 256 - d] : 0;
    __syncthreads();
    scan[t] += v0; scan[t + 256] += v1;
    __syncthreads();
  }
  for (int b = t; b < 512; b += 256) {
    int lo = scan[b] - hist[b];
    lofs[b] = lo;
    pcur[b] = lo;
    if (b < nb && hist[b]) base[b] = atomicAdd(&cursor[b], hist[b]);  // absolute
  }
  __syncthreads();
  for (int i = t; i < cnt; i += 256) {
    int d = dst[e0 + i];
    int b = d >> 8;
    int slot = atomicAdd(&pcur[b], 1);
    entry4[slot] = ((d & 255) << 24) | src[e0 + i];
    bin2[slot] = (short)b;
  }
  __syncthreads();
  for (int i = t; i < cnt; i += 256) {
    int b = bin2[i];
    bins[base[b] + (i - lofs[b])] = entry4[i];
  }
}

// ---- pass 2: per-bin counting sort by dl; emit run offsets, deg->dinv, y ----
__global__ void __launch_bounds__(1024) k_sortbin(int* __restrict__ bins,
                                                  const int* __restrict__ cursor,
                                                  const float* __restrict__ x,
                                                  float* __restrict__ dinv,
                                                  float* __restrict__ y,
                                                  int* __restrict__ roff, int n) {
  __shared__ int sorted[CAP];
  __shared__ int hist[RANGE], sc[RANGE], pcur[RANGE];
  int t = threadIdx.x;
  int b = blockIdx.x;
  int bse = b * CAP;
  int len = cursor[b] - bse;
  if (t < RANGE) hist[t] = 0;
  __syncthreads();
  for (int k = t; k < len; k += 1024)
    atomicAdd(&hist[((unsigned)bins[bse + k]) >> 24], 1);
  __syncthreads();
  if (t < RANGE) sc[t] = hist[t];
  __syncthreads();
  for (int d = 1; d < RANGE; d <<= 1) {
    int v = 0;
    if (t < RANGE && t >= d) v = sc[t - d];
    __syncthreads();
    if (t < RANGE) sc[t] += v;
    __syncthreads();
  }
  if (t < RANGE) pcur[t] = sc[t] - hist[t];
  __syncthreads();
  for (int k = t; k < len; k += 1024) {
    unsigned e4 = (unsigned)bins[bse + k];
    int slot = atomicAdd(&pcur[e4 >> 24], 1);
    sorted[slot] = (int)(e4 & 0xFFFFFF);
  }
  __syncthreads();
  for (int k = t; k < len; k += 1024) bins[bse + k] = sorted[k];
  if (t < RANGE) roff[b * (RANGE + 1) + t] = bse + sc[t] - hist[t];
  if (t == 0) roff[b * (RANGE + 1) + RANGE] = bse + len;
  if (t < RANGE) {
    int node = b * RANGE + t;
    if (node < n) {
      float dv = rsqrtf((float)(hist[t] + 1));
      dinv[node] = dv;
      float4 a, c;
      a.x = dv * x[node * 5 + 0];
      a.y = dv * x[node * 5 + 1];
      a.z = dv * x[node * 5 + 2];
      a.w = dv * x[node * 5 + 3];
      c.x = dv * x[node * 5 + 4];
      c.y = c.z = c.w = 0.f;
      ((float4*)y)[(size_t)node * 2 + 0] = a;
      ((float4*)y)[(size_t)node * 2 + 1] = c;
    }
  }
}

// ---- pass 3: layer-1 — atomic-free segmented gather + fused W1/relu/W2 -----
__global__ void __launch_bounds__(1024) k_agg1(const int* __restrict__ bins,
                                               const int* __restrict__ roff,
                                               const float* __restrict__ y,
                                               const float* __restrict__ dinv,
                                               const float* __restrict__ W1,
                                               const float* __restrict__ b1,
                                               const float* __restrict__ W2,
                                               float* __restrict__ z, int n) {
  __shared__ float sW1[80], sb1[16], sW2[16];
  int t = threadIdx.x;
  if (t < 80) sW1[t] = W1[t];
  else if (t < 96) sb1[t - 80] = b1[t - 80];
  else if (t < 112) sW2[t - 96] = W2[t - 96];
  __syncthreads();
  int g = t >> 2, l4 = t & 3;
  int b = blockIdx.x;
  int node = b * RANGE + g;
  if (node >= n) return;
  int r0 = roff[b * (RANGE + 1) + g];
  int r1 = roff[b * (RANGE + 1) + g + 1];
  float a0 = 0.f, a1 = 0.f, a2 = 0.f, a3 = 0.f, a4 = 0.f;
  for (int k = r0 + l4; k < r1; k += 4) {
    int s = bins[k];
    float4 v = ((const float4*)y)[(size_t)s * 2];
    float v4 = y[(size_t)s * 8 + 4];
    a0 += v.x; a1 += v.y; a2 += v.z; a3 += v.w; a4 += v4;
  }
  a0 += __shfl_xor(a0, 1); a0 += __shfl_xor(a0, 2);
  a1 += __shfl_xor(a1, 1); a1 += __shfl_xor(a1, 2);
  a2 += __shfl_xor(a2, 1); a2 += __shfl_xor(a2, 2);
  a3 += __shfl_xor(a3, 1); a3 += __shfl_xor(a3, 2);
  a4 += __shfl_xor(a4, 1); a4 += __shfl_xor(a4, 2);
  float4 ys = ((const float4*)y)[(size_t)node * 2];
  float ys4 = y[(size_t)node * 8 + 4];
  float A0 = a0 + ys.x, A1 = a1 + ys.y, A2 = a2 + ys.z, A3 = a3 + ys.w, A4 = a4 + ys4;
  float di = dinv[node];
  float o = 0.f;
#pragma unroll
  for (int fi = 0; fi < 4; ++fi) {
    int f = l4 * 4 + fi;
    float h = A0 * sW1[0 * 16 + f];
    h = fmaf(A1, sW1[1 * 16 + f], h);
    h = fmaf(A2, sW1[2 * 16 + f], h);
    h = fmaf(A3, sW1[3 * 16 + f], h);
    h = fmaf(A4, sW1[4 * 16 + f], h);
    float v = fmaxf(fmaf(di, h, sb1[f]), 0.f);
    o = fmaf(v, sW2[f], o);
  }
  o += __shfl_xor(o, 1);
  o += __shfl_xor(o, 2);
  if (l4 == 0) z[node] = di * o;
}

// ---- pass 4: layer-2 — atomic-free segmented gather of scalar z ------------
__global__ void __launch_bounds__(1024) k_agg2(const int* __restrict__ bins,
                                               const int* __restrict__ roff,
                                               const float* __restrict__ z,
                                               const float* __restrict__ dinv,
                                               const float* __restrict__ b2,
                                               float* __restrict__ out, int n) {
  int t = threadIdx.x;
  int g = t >> 2, l4 = t & 3;
  int b = blockIdx.x;
  int node = b * RANGE + g;
  if (node >= n) return;
  int r0 = roff[b * (RANGE + 1) + g];
  int r1 = roff[b * (RANGE + 1) + g + 1];
  float a = 0.f;
  for (int k = r0 + l4; k < r1; k += 4) a += z[bins[k]];
  a += __shfl_xor(a, 1);
  a += __shfl_xor(a, 2);
  if (l4 == 0) out[node] = fmaf(dinv[node], a + z[node], b2[0]);
}

extern "C" void kernel_launch(void* const* d_in, const int* in_sizes, int n_in,
                              void* d_out, int out_size, void* d_ws, size_t ws_size,
                              hipStream_t stream) {
  const float* x  = (const float*)d_in[0];
  const float* W1 = (const float*)d_in[1];
  const float* b1 = (const float*)d_in[2];
  const float* W2 = (const float*)d_in[3];
  const float* b2 = (const float*)d_in[4];
  const int*   ei = (const int*)d_in[5];

  int n = in_sizes[0] / 5;
  int e = in_sizes[5] / 2;
  const int* src = ei;
  const int* dst = ei + e;
  int nb = (n + RANGE - 1) / RANGE;  // 391

  char* ws = (char*)d_ws;
  int*   bins   = (int*)ws;   ws += (size_t)nb * CAP * sizeof(int);
  float* y      = (float*)ws; ws += (size_t)nb * RANGE * 8 * sizeof(float);
  float* dinv   = (float*)ws; ws += (size_t)n * sizeof(float);
  float* z      = (float*)ws; ws += (size_t)n * sizeof(float);
  int*   cursor = (int*)ws;   ws += (size_t)nb * sizeof(int);
  int*   roff   = (int*)ws;   ws += (size_t)nb * (RANGE + 1) * sizeof(int);

  float* out = (float*)d_out;

  int chunks = (e + CHUNK - 1) / CHUNK;

  k_init<<<(nb + 255) / 256, 256, 0, stream>>>(cursor, nb);
  k_place<<<chunks, 256, 0, stream>>>(src, dst, cursor, bins, e, nb);
  k_sortbin<<<nb, 1024, 0, stream>>>(bins, cursor, x, dinv, y, roff, n);
  k_agg1<<<nb, 1024, 0, stream>>>(bins, roff, y, dinv, W1, b1, W2, z, n);
  k_agg2<<<nb, 1024, 0, stream>>>(bins, roff, z, dinv, b2, out, n);
}